// Round 14
// baseline (143.828 us; speedup 1.0000x reference)
//
#include <hip/hip_runtime.h>

#define NDIM 2048
#define FDIM 64
#define KDIM 8
#define BDIM 32
#define TILE 64
#define BFROW 72   // bf16 elems per staging row (64 + 8 pad)

typedef __attribute__((ext_vector_type(8))) short short8;
typedef __attribute__((ext_vector_type(4))) float f32x4;

static __device__ __forceinline__ unsigned short f2bf(float x) {
    unsigned u = __float_as_uint(x);                 // RNE to bf16
    return (unsigned short)((u + 0x7fffu + ((u >> 16) & 1u)) >> 16);
}

// ---------------------------------------------------------------------------
// R14: direct-store epilogue, SCALAR mix (the discriminator test).
// Failed rounds R6/R7/R9 all consumed acc via f32x4 VECTOR arithmetic
// (pb[k]*acc) -> absmax ~20; every passing round mixed with SCALAR FMAs.
// This kernel = R9's structure (swapped MFMA operands -> store-native
// accumulator layout, zero-LDS zero-barrier epilogue) with the mix done in
// scalars only:
//   mfma(A = Am-frag(m-side), B = An-frag(n-side))   [R5 pinned: D-row<-A]
//   lane: D row = m-local = l4*4+reg (4 consecutive m), col = n-local = l15
//   -> out[n0+wr*32+tn*16+l15][m0+wc*32+tm*16+l4*4 .. +3] = one f32x4 store.
// Cov staging (bf16 LDS panels) + diagonal: verbatim from passing R5/R8.
// No XCD swizzle (single-variable change discipline).
// ---------------------------------------------------------------------------
__global__ __launch_bounds__(256, 2) void rfm_fused_mfma(
    const float* __restrict__ p, const float* __restrict__ L,
    const float* __restrict__ sr, float* __restrict__ out)
{
    __shared__ float pl[BDIM * KDIM];
    __shared__ __align__(16) unsigned short An[TILE][BFROW];
    __shared__ __align__(16) unsigned short Am[TILE][BFROW];

    const int n0 = blockIdx.y * TILE;
    const int m0 = blockIdx.x * TILE;
    const int t  = threadIdx.x;
    const int lane = t & 63;
    const int w   = t >> 6;        // wave 0..3
    const int wr  = w >> 1;        // n-side 32-block
    const int wc  = w & 1;         // m-side 32-block
    const int l15 = lane & 15;
    const int l4  = lane >> 4;     // 0..3

    pl[t] = p[t];                  // covered by first __syncthreads below

    f32x4 acc[KDIM][2][2];         // [k][tm][tn]
    #pragma unroll
    for (int k = 0; k < KDIM; ++k)
        #pragma unroll
        for (int tm = 0; tm < 2; ++tm)
            #pragma unroll
            for (int tn = 0; tn < 2; ++tn)
                acc[k][tm][tn] = (f32x4){0.f, 0.f, 0.f, 0.f};

    // ---- 1) cov phase: bf16 LDS staging (verbatim R5/R8) + swapped MFMA ----
    #pragma unroll
    for (int k = 0; k < KDIM; ++k) {
        const float* Lk = L + (size_t)k * (NDIM * FDIM);

        #pragma unroll
        for (int r = 0; r < 4; ++r) {
            const int idx = t + r * 256;
            const int row = idx >> 4;          // 16 float4 per row
            const int fc  = (idx & 15) << 2;
            const float4 va = *(const float4*)&Lk[(size_t)(n0 + row) * FDIM + fc];
            const float4 vb = *(const float4*)&Lk[(size_t)(m0 + row) * FDIM + fc];
            ushort4 ua, ub;
            ua.x = f2bf(va.x); ua.y = f2bf(va.y); ua.z = f2bf(va.z); ua.w = f2bf(va.w);
            ub.x = f2bf(vb.x); ub.y = f2bf(vb.y); ub.z = f2bf(vb.z); ub.w = f2bf(vb.w);
            *(ushort4*)&An[row][fc] = ua;
            *(ushort4*)&Am[row][fc] = ub;
        }
        __syncthreads();

        short8 af[2][2], bv[2][2];   // af: n-side frags, bv: m-side frags
        #pragma unroll
        for (int ti = 0; ti < 2; ++ti)
            #pragma unroll
            for (int s = 0; s < 2; ++s) {
                af[ti][s] = *(const short8*)
                    &An[wr * 32 + ti * 16 + l15][s * 32 + l4 * 8];
                bv[ti][s] = *(const short8*)
                    &Am[wc * 32 + ti * 16 + l15][s * 32 + l4 * 8];
            }
        #pragma unroll
        for (int tm = 0; tm < 2; ++tm)
            #pragma unroll
            for (int tn = 0; tn < 2; ++tn)
                #pragma unroll
                for (int s = 0; s < 2; ++s)
                    acc[k][tm][tn] = __builtin_amdgcn_mfma_f32_16x16x32_bf16(
                        bv[tm][s], af[tn][s], acc[k][tm][tn], 0, 0, 0);
        __syncthreads();   // panels consumed; next k may overwrite
    }

    // Diagonal: gn = n (col side, from B=af), gm = m (row side, from A=bv).
    #pragma unroll
    for (int tm = 0; tm < 2; ++tm)
        #pragma unroll
        for (int tn = 0; tn < 2; ++tn)
            #pragma unroll
            for (int reg = 0; reg < 4; ++reg) {
                const int gn = n0 + wr * 32 + tn * 16 + l15;
                const int gm = m0 + wc * 32 + tm * 16 + l4 * 4 + reg;
                if (gn == gm) {
                    #pragma unroll
                    for (int k = 0; k < KDIM; ++k) {
                        const float q = sr[k * NDIM + gn];
                        acc[k][tm][tn][reg] += q * q;
                    }
                }
            }

    // ---- 2) mix + store: SCALAR FMAs only, zero LDS, zero barriers ----
    const size_t NN = (size_t)NDIM * NDIM;
    float* optr[2][2];
    #pragma unroll
    for (int tm = 0; tm < 2; ++tm)
        #pragma unroll
        for (int tn = 0; tn < 2; ++tn)
            optr[tm][tn] = out
                + (size_t)(n0 + wr * 32 + tn * 16 + l15) * NDIM
                + (m0 + wc * 32 + tm * 16 + l4 * 4);

    #pragma unroll 1
    for (int b = 0; b < BDIM; ++b) {
        float pb[KDIM];
        #pragma unroll
        for (int k = 0; k < KDIM; ++k) pb[k] = pl[b * KDIM + k];
        const size_t boff = (size_t)b * NN;
        #pragma unroll
        for (int tm = 0; tm < 2; ++tm)
            #pragma unroll
            for (int tn = 0; tn < 2; ++tn) {
                float v0 = 0.f, v1 = 0.f, v2 = 0.f, v3 = 0.f;
                #pragma unroll
                for (int k = 0; k < KDIM; ++k) {
                    v0 += pb[k] * acc[k][tm][tn][0];
                    v1 += pb[k] * acc[k][tm][tn][1];
                    v2 += pb[k] * acc[k][tm][tn][2];
                    v3 += pb[k] * acc[k][tm][tn][3];
                }
                f32x4 r;
                r[0] = v0; r[1] = v1; r[2] = v2; r[3] = v3;
                *(f32x4*)(optr[tm][tn] + boff) = r;
            }
    }
}

extern "C" void kernel_launch(void* const* d_in, const int* in_sizes, int n_in,
                              void* d_out, int out_size, void* d_ws, size_t ws_size,
                              hipStream_t stream)
{
    const float* p  = (const float*)d_in[0];   // (B,K) = (32,8)
    const float* L  = (const float*)d_in[1];   // (K,N,F) = (8,2048,64)
    const float* sr = (const float*)d_in[2];   // (K,N)   = (8,2048)
    float* out = (float*)d_out;                // (B,N,N) = (32,2048,2048)

    dim3 grid(NDIM / TILE, NDIM / TILE);       // 32 x 32 = 1024 blocks
    hipLaunchKernelGGL(rfm_fused_mfma, grid, dim3(256), 0, stream,
                       p, L, sr, out);
}